// Round 7
// baseline (2698.742 us; speedup 1.0000x reference)
//
#include <hip/hip_runtime.h>

typedef short short8 __attribute__((ext_vector_type(8)));
typedef float f4 __attribute__((ext_vector_type(4)));

#define BATCH 128
#define SEQ   512
#define EMB   256
#define HID   256
#define G4    1024   // 4*HID

static __device__ __forceinline__ unsigned short f2b(float f) {
    union { float f; unsigned int u; } v; v.f = f;
    unsigned int u = v.u;
    return (unsigned short)((u + 0x7FFFu + ((u >> 16) & 1u)) >> 16);  // RNE
}
static __device__ __forceinline__ float b2f(unsigned short s) {
    union { unsigned int u; float f; } v; v.u = ((unsigned int)s) << 16;
    return v.f;
}

// ---------------- Kernel 0: convert weights to bf16, fold biases ----------------
__global__ void prep_kernel(const float* __restrict__ W_x, const float* __restrict__ U_h,
                            const float* __restrict__ b_x, const float* __restrict__ b_u,
                            const float* __restrict__ b_g,
                            unsigned short* __restrict__ w_xb, unsigned short* __restrict__ u_hb,
                            float* __restrict__ bias) {
    int i = blockIdx.x * blockDim.x + threadIdx.x;
    if (i < G4 * EMB) w_xb[i] = f2b(W_x[i]);
    if (i < G4 * HID) u_hb[i] = f2b(U_h[i]);
    if (i < G4) bias[i] = b_x[i] + b_u[i] + b_g[i];
}

// ---------------- Kernel 1: xp[s][b][g] = emb[tokens[b,s]] @ W_x^T + bias --------
// B-slice staged in LDS per n0 (shared by 4 waves): L2 B-traffic /4.
__global__ __launch_bounds__(256) void xp_gemm(
    const int* __restrict__ tokens, const float* __restrict__ emb,
    const unsigned short* __restrict__ w_xb, const float* __restrict__ bias,
    unsigned short* __restrict__ xp)
{
    __shared__ unsigned short As[64][264];   // A tile
    __shared__ unsigned short Bs[64][264];   // staged B slice
    __shared__ unsigned short Xs[64][72];    // store-transpose bounce
    const int m0 = blockIdx.x * 64;
    const int b  = m0 >> 9;          // m0 / SEQ
    const int s0 = m0 & 511;         // m0 % SEQ
    const int tid = threadIdx.x;
    const int cS = tid >> 2, qS = (tid & 3) * 64;   // staging map (A and B)
    {
        const int tok = tokens[m0 + cS];
        const float* src = emb + (long)tok * EMB + qS;
        #pragma unroll
        for (int i = 0; i < 8; ++i) {
            float4 v0 = ((const float4*)src)[2 * i];
            float4 v1 = ((const float4*)src)[2 * i + 1];
            short8 pk;
            pk[0] = (short)f2b(v0.x); pk[1] = (short)f2b(v0.y);
            pk[2] = (short)f2b(v0.z); pk[3] = (short)f2b(v0.w);
            pk[4] = (short)f2b(v1.x); pk[5] = (short)f2b(v1.y);
            pk[6] = (short)f2b(v1.z); pk[7] = (short)f2b(v1.w);
            *(short8*)&As[cS][qS + i * 8] = pk;
        }
    }
    __syncthreads();
    const int w = tid >> 6, l = tid & 63;
    const int ln = l & 15, hi = l >> 4;
    short8 a[8];
    #pragma unroll
    for (int kk = 0; kk < 8; ++kk)
        a[kk] = *(const short8*)&As[16 * w + ln][kk * 32 + hi * 8];

    const int rl = tid >> 2;            // global-store row (own wave's rows)
    const int cl = (tid & 3) * 16;      // global-store col offset in 64-tile

    for (int n0 = 0; n0 < G4; n0 += 64) {
        // stage B slice: Bs[c][k] = w_xb[(n0+c)*256 + k]
        {
            const unsigned short* src = &w_xb[(size_t)(n0 + cS) * EMB + qS];
            #pragma unroll
            for (int i = 0; i < 8; ++i)
                *(short8*)&Bs[cS][qS + i * 8] = *(const short8*)&src[i * 8];
        }
        __syncthreads();
        f4 acc[4] = {};
        #pragma unroll
        for (int kk = 0; kk < 8; ++kk) {
            #pragma unroll
            for (int nn = 0; nn < 4; ++nn) {
                short8 bfr = *(const short8*)&Bs[nn * 16 + ln][kk * 32 + hi * 8];
                acc[nn] = __builtin_amdgcn_mfma_f32_16x16x32_bf16(a[kk], bfr, acc[nn], 0, 0, 0);
            }
        }
        // bounce through LDS for coalesced b128 stores (same-wave rows: no barrier)
        #pragma unroll
        for (int nn = 0; nn < 4; ++nn) {
            const float bs = bias[n0 + nn * 16 + ln];
            #pragma unroll
            for (int r = 0; r < 4; ++r)
                Xs[16 * w + 4 * hi + r][nn * 16 + ln] = f2b(acc[nn][r] + bs);
        }
        size_t off = ((size_t)(s0 + rl) * BATCH + b) * G4 + n0 + cl;
        *(short8*)&xp[off]     = *(const short8*)&Xs[rl][cl];
        *(short8*)&xp[off + 8] = *(const short8*)&Xs[rl][cl + 8];
        __syncthreads();   // protect Bs before next staging
    }
}

// ---------------- Kernel 2: LSTM recurrence, 32 blocks x 4 rows, 16 waves -------
// Wave w owns hidden units [16w,16w+16); frag g = gate g of those units.
// U_h^T: kk0-3 in 64 VGPRs, kk4-5 streamed from L2 per step, kk6-7 in LDS (128 KB).
// Register budget 128 (waves_per_eu(4,4)): Br 64 + acc 16 + a 16 + stream 16 + ~16.
// LDS map (toggle-bit-safe bases): Blds [0,131072) | xlds 2x8192 @131072 (0x20000,
// bit-13 clear -> ^8192 valid) | hb 2x4096 @147456 (0x24000, bit-12 clear -> ^4096 valid)
__global__ void __launch_bounds__(1024) __attribute__((amdgpu_waves_per_eu(4, 4)))
lstm_recur(const unsigned short* __restrict__ xp,
           const unsigned short* __restrict__ u_hb,
           const float* __restrict__ fc_w, const float* __restrict__ fc_b,
           float* __restrict__ out)
{
    extern __shared__ char smem[];
    const int tid = threadIdx.x;
    const int w = tid >> 6, l = tid & 63;
    const int ln = l & 15, hi = l >> 4;
    const int b0 = blockIdx.x * 4;

    // preload B regs kk 0..3: 16 frags = 64 VGPRs
    short8 Br[4][4];
    #pragma unroll
    for (int kk = 0; kk < 4; ++kk)
        #pragma unroll
        for (int g = 0; g < 4; ++g) {
            const int col = g * HID + w * 16 + ln;
            Br[kk][g] = *(const short8*)&u_hb[(size_t)col * HID + kk * 32 + hi * 8];
        }
    // fill B LDS kk6-7: wave block 8KB: w*8192 + kkL*4096 + g*1024 + l*16
    {
        char* wbW = smem + w * 8192 + l * 16;
        #pragma unroll
        for (int kkL = 0; kkL < 2; ++kkL)
            #pragma unroll
            for (int g = 0; g < 4; ++g) {
                const int col = g * HID + w * 16 + ln;
                *(short8*)(wbW + kkL * 4096 + g * 1024) =
                    *(const short8*)&u_hb[(size_t)col * HID + (6 + kkL) * 32 + hi * 8];
            }
    }
    // zero both h buffers (8 KB at 147456; includes zero row 4)
    for (int i = tid; i < 2048; i += 1024) ((unsigned*)(smem + 147456))[i] = 0;
    // stage xp t=0 into xlds buf0 (reg -> ds_write, per-lane)
    if (w < 8) {
        short8 v = *(const short8*)&xp[(size_t)b0 * G4 + (size_t)(w * 64 + l) * 8];
        *(short8*)(smem + 131072 + w * 1024 + l * 16) = v;
    }
    __syncthreads();

    const int lnc = (ln < 4) ? ln : 4;                      // A rows 4..15 -> zero row
    int hbA = 147456 + lnc * 528 + hi * 16;                 // A-read base (cur=0)
    int hwr = 147456 + 4096 + hi * 528 + (w * 16 + ln) * 2; // h-write base (nxt=1)
    int xr  = 131072 + hi * 2048 + (w * 16 + ln) * 2;       // xp gate-read base (cur=0)
    int glo = 131072 + 8192 + w * 1024 + l * 16;            // stage-write dest (nxt=1)
    const unsigned short* gp = xp + ((size_t)BATCH + b0) * G4 + (size_t)(w * 64 + l) * 8; // t=1
    char* wb = smem + w * 8192 + l * 16;                    // Blds frag base
    const size_t scol[4] = { (size_t)(0 * HID + w * 16 + ln) * HID + hi * 8,
                             (size_t)(1 * HID + w * 16 + ln) * HID + hi * 8,
                             (size_t)(2 * HID + w * 16 + ln) * HID + hi * 8,
                             (size_t)(3 * HID + w * 16 + ln) * HID + hi * 8 };
    float c = 0.0f;

    for (int t = 0; t < SEQ; ++t) {
        const unsigned short* ub = u_hb;
        asm volatile("" : "+v"(ub));   // defeat LICM: keep streamed loads inside loop
        // prefetch next xp tile into regs (written to LDS at step end)
        short8 sv;
        const bool do_stage = (w < 8) & (t < SEQ - 1);
        if (do_stage) sv = *(const short8*)gp;
        gp += (size_t)BATCH * G4;

        // stream kk4 (consumed mid-sequence)
        short8 s4[4];
        #pragma unroll
        for (int g = 0; g < 4; ++g)
            s4[g] = *(const short8*)&ub[scol[g] + 4 * 32];

        f4 acc[4] = {};
        short8 a0, a1;
        a0 = *(const short8*)(smem + hbA);          // k0
        a1 = *(const short8*)(smem + hbA + 64);     // k1
        #pragma unroll
        for (int g = 0; g < 4; ++g) acc[g] = __builtin_amdgcn_mfma_f32_16x16x32_bf16(a0, Br[0][g], acc[g], 0, 0, 0);
        a0 = *(const short8*)(smem + hbA + 128);    // k2
        #pragma unroll
        for (int g = 0; g < 4; ++g) acc[g] = __builtin_amdgcn_mfma_f32_16x16x32_bf16(a1, Br[1][g], acc[g], 0, 0, 0);
        a1 = *(const short8*)(smem + hbA + 192);    // k3
        #pragma unroll
        for (int g = 0; g < 4; ++g) acc[g] = __builtin_amdgcn_mfma_f32_16x16x32_bf16(a0, Br[2][g], acc[g], 0, 0, 0);
        a0 = *(const short8*)(smem + hbA + 256);    // k4
        #pragma unroll
        for (int g = 0; g < 4; ++g) acc[g] = __builtin_amdgcn_mfma_f32_16x16x32_bf16(a1, Br[3][g], acc[g], 0, 0, 0);
        a1 = *(const short8*)(smem + hbA + 384);    // k6
        #pragma unroll
        for (int g = 0; g < 4; ++g)                 // kk4 (streamed)
            acc[g] = __builtin_amdgcn_mfma_f32_16x16x32_bf16(a0, s4[g], acc[g], 0, 0, 0);
        // stream kk5 now (s4 regs free; L2 latency hidden by kk6/kk7 MFMAs)
        short8 s5[4];
        #pragma unroll
        for (int g = 0; g < 4; ++g)
            s5[g] = *(const short8*)&ub[scol[g] + 5 * 32];
        a0 = *(const short8*)(smem + hbA + 448);    // k7
        #pragma unroll
        for (int g = 0; g < 4; ++g) {               // kk6 (LDS)
            short8 bl = *(const short8*)(wb + g * 1024);
            acc[g] = __builtin_amdgcn_mfma_f32_16x16x32_bf16(a1, bl, acc[g], 0, 0, 0);
        }
        a1 = *(const short8*)(smem + hbA + 320);    // k5
        #pragma unroll
        for (int g = 0; g < 4; ++g) {               // kk7 (LDS)
            short8 bl = *(const short8*)(wb + 4096 + g * 1024);
            acc[g] = __builtin_amdgcn_mfma_f32_16x16x32_bf16(a0, bl, acc[g], 0, 0, 0);
        }
        #pragma unroll
        for (int g = 0; g < 4; ++g)                 // kk5 (streamed)
            acc[g] = __builtin_amdgcn_mfma_f32_16x16x32_bf16(a1, s5[g], acc[g], 0, 0, 0);

        // gate compaction: lane (ln,hi) <- gates of (batch=hi, unit=16w+ln)
        float val[4];
        #pragma unroll
        for (int g = 0; g < 4; ++g) {
            float t0 = __shfl(acc[g][0], ln);
            float t1 = __shfl(acc[g][1], ln);
            float t2 = __shfl(acc[g][2], ln);
            float t3 = __shfl(acc[g][3], ln);
            float v = (hi == 0) ? t0 : (hi == 1) ? t1 : (hi == 2) ? t2 : t3;
            val[g] = v + b2f(*(const unsigned short*)(smem + xr + g * 512));
        }
        // LSTM cell: 5 exp + 3 rcp
        float ea = __expf(-val[0]);            // f-gate
        float ei = __expf(-val[1]);            // i-gate
        float eb = __expf(-2.0f * val[2]);     // tanh(c_hat)
        float eo = __expf(-val[3]);            // o-gate
        float rf = __builtin_amdgcn_rcpf(1.0f + ea);
        float it = (1.0f - eb) * __builtin_amdgcn_rcpf((1.0f + ei) * (1.0f + eb));
        float cn = fmaf(rf, c, it);
        c = cn;
        float ed = __expf(-2.0f * cn);         // tanh(c)
        float h = (1.0f - ed) * __builtin_amdgcn_rcpf((1.0f + eo) * (1.0f + ed));

        *(unsigned short*)(smem + hwr) = f2b(h);
        if (t == SEQ - 1)  // xlds buf0 idle at t=511 (reads are from buf1, no staging)
            *(float*)(smem + 131072 + hi * 1024 + (w * 16 + ln) * 4) = h;
        if (do_stage)
            *(short8*)(smem + glo) = sv;
        hbA ^= 4096; hwr ^= 4096; xr ^= 8192; glo ^= 8192;
        __syncthreads();
    }

    // epilogue: out[b0+r][o] = fc_b[o] + sum_j h[r][j]*fc_w[o][j]
    if (tid < 64) {
        const float* hf32 = (const float*)(smem + 131072);
        const int r = tid >> 4, o = (tid >> 3) & 1, j0 = tid & 7;
        float s = 0.0f;
        for (int j = j0; j < HID; j += 8)
            s += hf32[r * 256 + j] * fc_w[o * HID + j];
        s += __shfl_down(s, 4);
        s += __shfl_down(s, 2);
        s += __shfl_down(s, 1);
        if (j0 == 0) out[(b0 + r) * 2 + o] = fc_b[o] + s;
    }
}

extern "C" void kernel_launch(void* const* d_in, const int* in_sizes, int n_in,
                              void* d_out, int out_size, void* d_ws, size_t ws_size,
                              hipStream_t stream) {
    const int*   tokens = (const int*)  d_in[0];
    const float* emb    = (const float*)d_in[1];
    const float* W_x    = (const float*)d_in[2];
    const float* b_x    = (const float*)d_in[3];
    const float* U_h    = (const float*)d_in[4];
    const float* b_u    = (const float*)d_in[5];
    const float* b_g    = (const float*)d_in[6];
    const float* fc_w   = (const float*)d_in[7];
    const float* fc_b   = (const float*)d_in[8];
    float* out = (float*)d_out;

    char* ws = (char*)d_ws;
    unsigned short* w_xb = (unsigned short*)(ws);                 // 512 KB
    unsigned short* u_hb = (unsigned short*)(ws + 524288);        // 512 KB
    float*          bias = (float*)(ws + 1048576);                // 4 KB
    unsigned short* xp   = (unsigned short*)(ws + 1052672);       // 128 MB bf16 [S][B][4H]

    prep_kernel<<<1024, 256, 0, stream>>>(W_x, U_h, b_x, b_u, b_g, w_xb, u_hb, bias);
    xp_gemm<<<1024, 256, 0, stream>>>(tokens, emb, w_xb, bias, xp);

    (void)hipFuncSetAttribute((const void*)lstm_recur,
                              hipFuncAttributeMaxDynamicSharedMemorySize, 155648);
    lstm_recur<<<32, 1024, 155648, stream>>>(xp, u_hb, fc_w, fc_b, out);
}

// Round 8
// 2163.372 us; speedup vs baseline: 1.2475x; 1.2475x over previous
//
#include <hip/hip_runtime.h>

typedef short short8 __attribute__((ext_vector_type(8)));
typedef float f4 __attribute__((ext_vector_type(4)));

#define BATCH 128
#define SEQ   512
#define EMB   256
#define HID   256
#define G4    1024   // 4*HID

static __device__ __forceinline__ unsigned short f2b(float f) {
    union { float f; unsigned int u; } v; v.f = f;
    unsigned int u = v.u;
    return (unsigned short)((u + 0x7FFFu + ((u >> 16) & 1u)) >> 16);  // RNE
}
static __device__ __forceinline__ float b2f(unsigned short s) {
    union { unsigned int u; float f; } v; v.u = ((unsigned int)s) << 16;
    return v.f;
}

// ---------------- Kernel 0: convert weights, fold biases, zero sync state -------
__global__ void prep_kernel(const float* __restrict__ W_x, const float* __restrict__ U_h,
                            const float* __restrict__ b_x, const float* __restrict__ b_u,
                            const float* __restrict__ b_g,
                            unsigned short* __restrict__ w_xb, unsigned short* __restrict__ u_hb,
                            float* __restrict__ bias,
                            unsigned int* __restrict__ flags, unsigned int* __restrict__ hx32,
                            float* __restrict__ out) {
    int i = blockIdx.x * blockDim.x + threadIdx.x;
    if (i < G4 * EMB) w_xb[i] = f2b(W_x[i]);
    if (i < G4 * HID) u_hb[i] = f2b(U_h[i]);
    if (i < G4) bias[i] = b_x[i] + b_u[i] + b_g[i];
    if (i < 32768) hx32[i] = 0;      // both hx buffers (131072 B)
    if (i < 16) flags[i] = 0;        // per-block step counters (every launch!)
    if (i < 256) out[i] = 0.0f;      // out is atomicAdd-accumulated
}

// ---------------- Kernel 1: xp[s][b][g] = emb[tokens[b,s]] @ W_x^T + bias --------
__global__ __launch_bounds__(256) void xp_gemm(
    const int* __restrict__ tokens, const float* __restrict__ emb,
    const unsigned short* __restrict__ w_xb, const float* __restrict__ bias,
    unsigned short* __restrict__ xp)
{
    __shared__ unsigned short As[64][264];   // A tile
    __shared__ unsigned short Bs[64][264];   // staged B slice
    __shared__ unsigned short Xs[64][72];    // store-transpose bounce
    const int m0 = blockIdx.x * 64;
    const int b  = m0 >> 9;          // m0 / SEQ
    const int s0 = m0 & 511;         // m0 % SEQ
    const int tid = threadIdx.x;
    const int cS = tid >> 2, qS = (tid & 3) * 64;   // staging map (A and B)
    {
        const int tok = tokens[m0 + cS];
        const float* src = emb + (long)tok * EMB + qS;
        #pragma unroll
        for (int i = 0; i < 8; ++i) {
            float4 v0 = ((const float4*)src)[2 * i];
            float4 v1 = ((const float4*)src)[2 * i + 1];
            short8 pk;
            pk[0] = (short)f2b(v0.x); pk[1] = (short)f2b(v0.y);
            pk[2] = (short)f2b(v0.z); pk[3] = (short)f2b(v0.w);
            pk[4] = (short)f2b(v1.x); pk[5] = (short)f2b(v1.y);
            pk[6] = (short)f2b(v1.z); pk[7] = (short)f2b(v1.w);
            *(short8*)&As[cS][qS + i * 8] = pk;
        }
    }
    __syncthreads();
    const int w = tid >> 6, l = tid & 63;
    const int ln = l & 15, hi = l >> 4;
    short8 a[8];
    #pragma unroll
    for (int kk = 0; kk < 8; ++kk)
        a[kk] = *(const short8*)&As[16 * w + ln][kk * 32 + hi * 8];

    const int rl = tid >> 2;            // global-store row (own wave's rows)
    const int cl = (tid & 3) * 16;      // global-store col offset in 64-tile

    for (int n0 = 0; n0 < G4; n0 += 64) {
        {
            const unsigned short* src = &w_xb[(size_t)(n0 + cS) * EMB + qS];
            #pragma unroll
            for (int i = 0; i < 8; ++i)
                *(short8*)&Bs[cS][qS + i * 8] = *(const short8*)&src[i * 8];
        }
        __syncthreads();
        f4 acc[4] = {};
        #pragma unroll
        for (int kk = 0; kk < 8; ++kk) {
            #pragma unroll
            for (int nn = 0; nn < 4; ++nn) {
                short8 bfr = *(const short8*)&Bs[nn * 16 + ln][kk * 32 + hi * 8];
                acc[nn] = __builtin_amdgcn_mfma_f32_16x16x32_bf16(a[kk], bfr, acc[nn], 0, 0, 0);
            }
        }
        #pragma unroll
        for (int nn = 0; nn < 4; ++nn) {
            const float bs = bias[n0 + nn * 16 + ln];
            #pragma unroll
            for (int r = 0; r < 4; ++r)
                Xs[16 * w + 4 * hi + r][nn * 16 + ln] = f2b(acc[nn][r] + bs);
        }
        size_t off = ((size_t)(s0 + rl) * BATCH + b) * G4 + n0 + cl;
        *(short8*)&xp[off]     = *(const short8*)&Xs[rl][cl];
        *(short8*)&xp[off + 8] = *(const short8*)&Xs[rl][cl + 8];
        __syncthreads();
    }
}

// ---------------- Kernel 2: LSTM, 16 blocks = 8 batch-groups x 2 unit-halves ----
// Block (g, half): batch rows 16g..16g+16, units half*128..+128 (all 4 gates).
// Wave w owns 16 units; acc lanes map 1:1 to (row,unit) cells -> no compaction.
// B-half (256 KB): 6 K-slices in 96 VGPRs, 2 in LDS (64 KB).
// Per-step pairwise h-exchange via device-scope atomics (hx dbuf + flag counter).
// LDS: Blds [0,65536) | hb 2x[16][264]us @65536,81920 (^16384 toggle, base bit-14 clear)
__global__ void __launch_bounds__(512, 2)
lstm_recur(const unsigned short* __restrict__ xp,
           const unsigned short* __restrict__ u_hb,
           const float* __restrict__ fc_w, const float* __restrict__ fc_b,
           unsigned short* __restrict__ hx, unsigned int* __restrict__ flags,
           float* __restrict__ out)
{
    extern __shared__ char smem[];
    const int tid = threadIdx.x;
    const int w = tid >> 6, l = tid & 63;
    const int ln = l & 15, hi = l >> 4;
    const int bid = blockIdx.x;
    const int g = bid >> 1, half = bid & 1, ph = half ^ 1;
    const int k_own = 4 * half, k_par = 4 * ph;   // K-slice bases (units = K dim)

    // preload B regs: own slices k_own+{0,1,2}, partner k_par+{0,1,2} (96 VGPRs)
    short8 Br[6][4];
    #pragma unroll
    for (int j = 0; j < 6; ++j) {
        const int kk = (j < 3) ? (k_own + j) : (k_par + j - 3);
        #pragma unroll
        for (int q = 0; q < 4; ++q) {
            const int col = q * 256 + half * 128 + w * 16 + ln;
            Br[j][q] = *(const short8*)&u_hb[(size_t)col * HID + kk * 32 + hi * 8];
        }
    }
    // B LDS: kkL0 = k_own+3, kkL1 = k_par+3 (lane-private frags, 64 KB)
    #pragma unroll
    for (int kkL = 0; kkL < 2; ++kkL) {
        const int kk = (kkL == 0) ? (k_own + 3) : (k_par + 3);
        #pragma unroll
        for (int q = 0; q < 4; ++q) {
            const int col = q * 256 + half * 128 + w * 16 + ln;
            *(short8*)(smem + kkL * 32768 + w * 4096 + q * 1024 + l * 16) =
                *(const short8*)&u_hb[(size_t)col * HID + kk * 32 + hi * 8];
        }
    }
    // zero both h buffers (32 KB @ 65536)
    for (int i = tid; i < 8192; i += 512) ((unsigned*)(smem + 65536))[i] = 0;
    __syncthreads();

    const unsigned int* pf = flags + (bid ^ 1);
    unsigned int* mf = flags + bid;
    // copy-in mapping: thread -> (row, 4 units) of partner half
    const int crow = tid >> 5, cuo = (tid & 31) * 4;
    // gate-cell mapping: lane -> rows 4hi..4hi+4, unit w*16+ln (+half*128 global)
    const int uin = w * 16 + ln;           // unit index within half
    float c[4] = {0.f, 0.f, 0.f, 0.f};

    for (int t = 0; t < SEQ; ++t) {
        const int cur = t & 1;
        const int hbc = 65536 + (cur << 14);
        const int hbn = hbc ^ 16384;

        // xp for this step: 16 scalar u16 loads, issued early, used at gate phase
        const unsigned short* xb = xp + ((size_t)(t * 128 + 16 * g + 4 * hi)) * 1024
                                      + half * 128 + uin;
        unsigned short xv[4][4];
        #pragma unroll
        for (int q = 0; q < 4; ++q)
            #pragma unroll
            for (int r = 0; r < 4; ++r)
                xv[q][r] = xb[r * 1024 + q * 256];

        // own-half MFMA (partner h not needed yet)
        f4 acc[4] = {};
        short8 av;
        #pragma unroll
        for (int j = 0; j < 3; ++j) {
            av = *(const short8*)(smem + hbc + ln * 528 + (k_own + j) * 64 + hi * 16);
            #pragma unroll
            for (int q = 0; q < 4; ++q)
                acc[q] = __builtin_amdgcn_mfma_f32_16x16x32_bf16(av, Br[j][q], acc[q], 0, 0, 0);
        }
        av = *(const short8*)(smem + hbc + ln * 528 + (k_own + 3) * 64 + hi * 16);
        #pragma unroll
        for (int q = 0; q < 4; ++q) {
            short8 bl = *(const short8*)(smem + w * 4096 + q * 1024 + l * 16);  // kkL0
            acc[q] = __builtin_amdgcn_mfma_f32_16x16x32_bf16(av, bl, acc[q], 0, 0, 0);
        }

        // wait for partner h(t-1), copy its half into hb[cur]
        if (t > 0)
            while (__hip_atomic_load(pf, __ATOMIC_ACQUIRE, __HIP_MEMORY_SCOPE_AGENT) < (unsigned)t) {}
        {
            const size_t sidx = ((size_t)((cur ^ 1) * 8 + g) * 2 + ph) * 2048 + crow * 128 + cuo;
            unsigned long long v = __hip_atomic_load((const unsigned long long*)(hx + sidx),
                                                     __ATOMIC_RELAXED, __HIP_MEMORY_SCOPE_AGENT);
            *(unsigned long long*)(smem + hbc + crow * 528 + (ph * 128 + cuo) * 2) = v;
        }
        __syncthreads();

        // partner-half MFMA
        #pragma unroll
        for (int j = 0; j < 3; ++j) {
            av = *(const short8*)(smem + hbc + ln * 528 + (k_par + j) * 64 + hi * 16);
            #pragma unroll
            for (int q = 0; q < 4; ++q)
                acc[q] = __builtin_amdgcn_mfma_f32_16x16x32_bf16(av, Br[3 + j][q], acc[q], 0, 0, 0);
        }
        av = *(const short8*)(smem + hbc + ln * 528 + (k_par + 3) * 64 + hi * 16);
        #pragma unroll
        for (int q = 0; q < 4; ++q) {
            short8 bl = *(const short8*)(smem + 32768 + w * 4096 + q * 1024 + l * 16);  // kkL1
            acc[q] = __builtin_amdgcn_mfma_f32_16x16x32_bf16(av, bl, acc[q], 0, 0, 0);
        }

        // gates: lane owns 4 cells (rows 4hi+r, unit uin) — all in-register
        unsigned short hu[4];
        #pragma unroll
        for (int r = 0; r < 4; ++r) {
            float vf = acc[0][r] + b2f(xv[0][r]);
            float vi = acc[1][r] + b2f(xv[1][r]);
            float vc = acc[2][r] + b2f(xv[2][r]);
            float vo = acc[3][r] + b2f(xv[3][r]);
            float ea = __expf(-vf);
            float ei = __expf(-vi);
            float eb = __expf(-2.0f * vc);
            float eo = __expf(-vo);
            float rf = __builtin_amdgcn_rcpf(1.0f + ea);
            float it = (1.0f - eb) * __builtin_amdgcn_rcpf((1.0f + ei) * (1.0f + eb));
            float cn = fmaf(rf, c[r], it);
            c[r] = cn;
            float ed = __expf(-2.0f * cn);
            float h = (1.0f - ed) * __builtin_amdgcn_rcpf((1.0f + eo) * (1.0f + ed));
            hu[r] = f2b(h);
            *(unsigned short*)(smem + hbn + (4 * hi + r) * 528 + (half * 128 + uin) * 2) = hu[r];
        }
        // publish own half: even lanes store packed u32 (device-coherent)
        #pragma unroll
        for (int r = 0; r < 4; ++r) {
            int ot = __shfl_xor((int)hu[r], 1);
            if ((ln & 1) == 0) {
                unsigned int pv = (unsigned int)hu[r] | ((unsigned int)ot << 16);
                const size_t di = ((size_t)(cur * 8 + g) * 2 + half) * 1024
                                + (4 * hi + r) * 64 + (uin >> 1);
                __hip_atomic_store((unsigned int*)hx + di, pv,
                                   __ATOMIC_RELAXED, __HIP_MEMORY_SCOPE_AGENT);
            }
        }
        __syncthreads();   // drains vmcnt per wave before barrier -> stores visible
        if (tid == 0)
            __hip_atomic_store(mf, (unsigned)(t + 1), __ATOMIC_RELEASE, __HIP_MEMORY_SCOPE_AGENT);
    }

    // epilogue: partial FC over own 128 units, atomicAdd (2 deterministic addends)
    if (tid < 32) {
        const int r = tid >> 1, o = tid & 1;
        float s = (half == 0) ? fc_b[o] : 0.0f;
        const char* hrow = smem + 65536 + r * 528 + half * 256;  // h(511) lives in buf0
        for (int j = 0; j < 128; ++j)
            s += b2f(*(const unsigned short*)(hrow + j * 2)) * fc_w[o * HID + half * 128 + j];
        atomicAdd(&out[(16 * g + r) * 2 + o], s);
    }
}

extern "C" void kernel_launch(void* const* d_in, const int* in_sizes, int n_in,
                              void* d_out, int out_size, void* d_ws, size_t ws_size,
                              hipStream_t stream) {
    const int*   tokens = (const int*)  d_in[0];
    const float* emb    = (const float*)d_in[1];
    const float* W_x    = (const float*)d_in[2];
    const float* b_x    = (const float*)d_in[3];
    const float* U_h    = (const float*)d_in[4];
    const float* b_u    = (const float*)d_in[5];
    const float* b_g    = (const float*)d_in[6];
    const float* fc_w   = (const float*)d_in[7];
    const float* fc_b   = (const float*)d_in[8];
    float* out = (float*)d_out;

    char* ws = (char*)d_ws;
    unsigned short* w_xb  = (unsigned short*)(ws);                 // 512 KB
    unsigned short* u_hb  = (unsigned short*)(ws + 524288);        // 512 KB
    float*          bias  = (float*)(ws + 1048576);                // 4 KB
    unsigned int*   flags = (unsigned int*)(ws + 1052672);         // 64 B (pad 4 KB)
    unsigned short* hx    = (unsigned short*)(ws + 1056768);       // 128 KB [2][8][2][16][128]
    unsigned short* xp    = (unsigned short*)(ws + 1187840);       // 128 MB bf16 [S][B][4H]

    prep_kernel<<<1024, 256, 0, stream>>>(W_x, U_h, b_x, b_u, b_g, w_xb, u_hb, bias,
                                          flags, (unsigned int*)hx, out);
    xp_gemm<<<1024, 256, 0, stream>>>(tokens, emb, w_xb, bias, xp);

    (void)hipFuncSetAttribute((const void*)lstm_recur,
                              hipFuncAttributeMaxDynamicSharedMemorySize, 98304);
    lstm_recur<<<16, 512, 98304, stream>>>(xp, u_hb, fc_w, fc_b, hx, flags, out);
}

// Round 9
// 2126.672 us; speedup vs baseline: 1.2690x; 1.0173x over previous
//
#include <hip/hip_runtime.h>

typedef short short8 __attribute__((ext_vector_type(8)));
typedef float f4 __attribute__((ext_vector_type(4)));

#define BATCH 128
#define SEQ   512
#define EMB   256
#define HID   256
#define G4    1024   // 4*HID

static __device__ __forceinline__ unsigned short f2b(float f) {
    union { float f; unsigned int u; } v; v.f = f;
    unsigned int u = v.u;
    return (unsigned short)((u + 0x7FFFu + ((u >> 16) & 1u)) >> 16);  // RNE
}
static __device__ __forceinline__ float b2f(unsigned short s) {
    union { unsigned int u; float f; } v; v.u = ((unsigned int)s) << 16;
    return v.f;
}

// ---------------- Kernel 0: convert weights, fold biases, zero sync state -------
__global__ void prep_kernel(const float* __restrict__ W_x, const float* __restrict__ U_h,
                            const float* __restrict__ b_x, const float* __restrict__ b_u,
                            const float* __restrict__ b_g,
                            unsigned short* __restrict__ w_xb, unsigned short* __restrict__ u_hb,
                            float* __restrict__ bias,
                            unsigned int* __restrict__ flags, unsigned int* __restrict__ hx32,
                            float* __restrict__ out) {
    int i = blockIdx.x * blockDim.x + threadIdx.x;
    if (i < G4 * EMB) w_xb[i] = f2b(W_x[i]);
    if (i < G4 * HID) u_hb[i] = f2b(U_h[i]);
    if (i < G4) bias[i] = b_x[i] + b_u[i] + b_g[i];
    if (i < 32768) hx32[i] = 0;      // both hx buffers (131072 B)
    if (i < 16) flags[i] = 0;        // per-block step counters (every launch!)
    if (i < 256) out[i] = 0.0f;      // out is atomicAdd-accumulated
}

// ---------------- Kernel 1: xp[s][b][g] = emb[tokens[b,s]] @ W_x^T + bias --------
__global__ __launch_bounds__(256) void xp_gemm(
    const int* __restrict__ tokens, const float* __restrict__ emb,
    const unsigned short* __restrict__ w_xb, const float* __restrict__ bias,
    unsigned short* __restrict__ xp)
{
    __shared__ unsigned short As[64][264];   // A tile
    __shared__ unsigned short Bs[64][264];   // staged B slice
    __shared__ unsigned short Xs[64][72];    // store-transpose bounce
    const int m0 = blockIdx.x * 64;
    const int b  = m0 >> 9;          // m0 / SEQ
    const int s0 = m0 & 511;         // m0 % SEQ
    const int tid = threadIdx.x;
    const int cS = tid >> 2, qS = (tid & 3) * 64;   // staging map (A and B)
    {
        const int tok = tokens[m0 + cS];
        const float* src = emb + (long)tok * EMB + qS;
        #pragma unroll
        for (int i = 0; i < 8; ++i) {
            float4 v0 = ((const float4*)src)[2 * i];
            float4 v1 = ((const float4*)src)[2 * i + 1];
            short8 pk;
            pk[0] = (short)f2b(v0.x); pk[1] = (short)f2b(v0.y);
            pk[2] = (short)f2b(v0.z); pk[3] = (short)f2b(v0.w);
            pk[4] = (short)f2b(v1.x); pk[5] = (short)f2b(v1.y);
            pk[6] = (short)f2b(v1.z); pk[7] = (short)f2b(v1.w);
            *(short8*)&As[cS][qS + i * 8] = pk;
        }
    }
    __syncthreads();
    const int w = tid >> 6, l = tid & 63;
    const int ln = l & 15, hi = l >> 4;
    short8 a[8];
    #pragma unroll
    for (int kk = 0; kk < 8; ++kk)
        a[kk] = *(const short8*)&As[16 * w + ln][kk * 32 + hi * 8];

    const int rl = tid >> 2;            // global-store row (own wave's rows)
    const int cl = (tid & 3) * 16;      // global-store col offset in 64-tile

    for (int n0 = 0; n0 < G4; n0 += 64) {
        {
            const unsigned short* src = &w_xb[(size_t)(n0 + cS) * EMB + qS];
            #pragma unroll
            for (int i = 0; i < 8; ++i)
                *(short8*)&Bs[cS][qS + i * 8] = *(const short8*)&src[i * 8];
        }
        __syncthreads();
        f4 acc[4] = {};
        #pragma unroll
        for (int kk = 0; kk < 8; ++kk) {
            #pragma unroll
            for (int nn = 0; nn < 4; ++nn) {
                short8 bfr = *(const short8*)&Bs[nn * 16 + ln][kk * 32 + hi * 8];
                acc[nn] = __builtin_amdgcn_mfma_f32_16x16x32_bf16(a[kk], bfr, acc[nn], 0, 0, 0);
            }
        }
        #pragma unroll
        for (int nn = 0; nn < 4; ++nn) {
            const float bs = bias[n0 + nn * 16 + ln];
            #pragma unroll
            for (int r = 0; r < 4; ++r)
                Xs[16 * w + 4 * hi + r][nn * 16 + ln] = f2b(acc[nn][r] + bs);
        }
        size_t off = ((size_t)(s0 + rl) * BATCH + b) * G4 + n0 + cl;
        *(short8*)&xp[off]     = *(const short8*)&Xs[rl][cl];
        *(short8*)&xp[off + 8] = *(const short8*)&Xs[rl][cl + 8];
        __syncthreads();
    }
}

// ---------------- Kernel 2: LSTM, 16 blocks = 8 batch-groups x 2 unit-halves ----
// SAME-XCD pairing: g = bid&7, half = bid>>3, partner = bid^8 (round-robin XCDs
// -> pair shares an XCD; perf heuristic only, protocol is order-independent).
// Block (g, half): batch rows 16g..16g+16, units half*128..+128 (all 4 gates).
// B-half (256 KB): 6 K-slices in 96 VGPRs, 2 in LDS (64 KB).
// xp staged via LDS dbuf, reg-prefetch of t+1 during step t.
// LDS map: Blds [0,65536) | hb 2x8448 @65536/81920 (^16384) | xlds 2x16384 @98304 (^16384)
__global__ void __launch_bounds__(512, 2)
lstm_recur(const unsigned short* __restrict__ xp,
           const unsigned short* __restrict__ u_hb,
           const float* __restrict__ fc_w, const float* __restrict__ fc_b,
           unsigned short* __restrict__ hx, unsigned int* __restrict__ flags,
           float* __restrict__ out)
{
    extern __shared__ char smem[];
    const int tid = threadIdx.x;
    const int w = tid >> 6, l = tid & 63;
    const int ln = l & 15, hi = l >> 4;
    const int bid = blockIdx.x;
    const int g = bid & 7, half = bid >> 3, ph = half ^ 1;
    const int k_own = 4 * half, k_par = 4 * ph;   // K-slice bases (units = K dim)

    // preload B regs: own slices k_own+{0,1,2}, partner k_par+{0,1,2} (96 VGPRs)
    short8 Br[6][4];
    #pragma unroll
    for (int j = 0; j < 6; ++j) {
        const int kk = (j < 3) ? (k_own + j) : (k_par + j - 3);
        #pragma unroll
        for (int q = 0; q < 4; ++q) {
            const int col = q * 256 + half * 128 + w * 16 + ln;
            Br[j][q] = *(const short8*)&u_hb[(size_t)col * HID + kk * 32 + hi * 8];
        }
    }
    // B LDS: kkL0 = k_own+3, kkL1 = k_par+3 (lane-private frags, 64 KB)
    #pragma unroll
    for (int kkL = 0; kkL < 2; ++kkL) {
        const int kk = (kkL == 0) ? (k_own + 3) : (k_par + 3);
        #pragma unroll
        for (int q = 0; q < 4; ++q) {
            const int col = q * 256 + half * 128 + w * 16 + ln;
            *(short8*)(smem + kkL * 32768 + w * 4096 + q * 1024 + l * 16) =
                *(const short8*)&u_hb[(size_t)col * HID + kk * 32 + hi * 8];
        }
    }
    // zero both h buffers (2 x 8448 B @ 65536/81920)
    for (int i = tid; i < 4224; i += 512) ((unsigned*)(smem + 65536))[i] = 0;
    for (int i = tid; i < 4224; i += 512) ((unsigned*)(smem + 81920))[i] = 0;

    // xp staging geometry: thread -> (row = tid>>5, two 16B segs s0, s0+1)
    const int row = tid >> 5, s0 = (tid & 31) * 2;
    const size_t xoff = (size_t)(16 * g + row) * 1024 + (s0 >> 4) * 256 + half * 128 + (s0 & 15) * 8;
    const int xdst = row * 1024 + s0 * 16;   // byte offset within xlds buffer
    // prologue: stage t=0 into xlds buf0
    {
        const unsigned short* src = xp + xoff;
        *(short8*)(smem + 98304 + xdst)      = *(const short8*)src;
        *(short8*)(smem + 98304 + xdst + 16) = *(const short8*)(src + 8);
    }
    __syncthreads();

    const unsigned int* pf = flags + (bid ^ 8);
    unsigned int* mf = flags + bid;
    // copy-in mapping: thread -> (row, 4 units) of partner half
    const int crow = tid >> 5, cuo = (tid & 31) * 4;
    // gate-cell mapping: lane -> rows 4hi..4hi+4, unit w*16+ln (+half*128 global)
    const int uin = w * 16 + ln;           // unit index within half
    float c[4] = {0.f, 0.f, 0.f, 0.f};

    for (int t = 0; t < SEQ; ++t) {
        const int cur = t & 1;
        const int hbc = 65536 + (cur << 14);
        const int hbn = hbc ^ 16384;
        const int xcur = 98304 + (cur << 14);
        const int xnxt = xcur ^ 16384;

        // prefetch next xp tile into regs (written to LDS at step end)
        short8 sv0, sv1;
        const bool do_stage = (t + 1 < SEQ);
        if (do_stage) {
            const unsigned short* src = xp + (size_t)(t + 1) * 131072 + xoff;
            sv0 = *(const short8*)src;
            sv1 = *(const short8*)(src + 8);
        }

        // own-half MFMA (partner h not needed yet)
        f4 acc[4] = {};
        short8 av;
        #pragma unroll
        for (int j = 0; j < 3; ++j) {
            av = *(const short8*)(smem + hbc + ln * 528 + (k_own + j) * 64 + hi * 16);
            #pragma unroll
            for (int q = 0; q < 4; ++q)
                acc[q] = __builtin_amdgcn_mfma_f32_16x16x32_bf16(av, Br[j][q], acc[q], 0, 0, 0);
        }
        av = *(const short8*)(smem + hbc + ln * 528 + (k_own + 3) * 64 + hi * 16);
        #pragma unroll
        for (int q = 0; q < 4; ++q) {
            short8 bl = *(const short8*)(smem + w * 4096 + q * 1024 + l * 16);  // kkL0
            acc[q] = __builtin_amdgcn_mfma_f32_16x16x32_bf16(av, bl, acc[q], 0, 0, 0);
        }

        // wait for partner h(t-1), copy its half into hb[cur]
        if (t > 0)
            while (__hip_atomic_load(pf, __ATOMIC_ACQUIRE, __HIP_MEMORY_SCOPE_AGENT) < (unsigned)t) {}
        {
            const size_t sidx = ((size_t)((cur ^ 1) * 8 + g) * 2 + ph) * 2048 + crow * 128 + cuo;
            unsigned long long v = __hip_atomic_load((const unsigned long long*)(hx + sidx),
                                                     __ATOMIC_RELAXED, __HIP_MEMORY_SCOPE_AGENT);
            *(unsigned long long*)(smem + hbc + crow * 528 + (ph * 128 + cuo) * 2) = v;
        }
        __syncthreads();

        // partner-half MFMA
        #pragma unroll
        for (int j = 0; j < 3; ++j) {
            av = *(const short8*)(smem + hbc + ln * 528 + (k_par + j) * 64 + hi * 16);
            #pragma unroll
            for (int q = 0; q < 4; ++q)
                acc[q] = __builtin_amdgcn_mfma_f32_16x16x32_bf16(av, Br[3 + j][q], acc[q], 0, 0, 0);
        }
        av = *(const short8*)(smem + hbc + ln * 528 + (k_par + 3) * 64 + hi * 16);
        #pragma unroll
        for (int q = 0; q < 4; ++q) {
            short8 bl = *(const short8*)(smem + 32768 + w * 4096 + q * 1024 + l * 16);  // kkL1
            acc[q] = __builtin_amdgcn_mfma_f32_16x16x32_bf16(av, bl, acc[q], 0, 0, 0);
        }

        // gates: lane owns 4 cells (rows 4hi+r, unit uin) — xp read from LDS
        unsigned short hu[4];
        #pragma unroll
        for (int r = 0; r < 4; ++r) {
            const int xrb = xcur + (4 * hi + r) * 1024 + uin * 2;
            float vf = acc[0][r] + b2f(*(const unsigned short*)(smem + xrb));
            float vi = acc[1][r] + b2f(*(const unsigned short*)(smem + xrb + 256));
            float vc = acc[2][r] + b2f(*(const unsigned short*)(smem + xrb + 512));
            float vo = acc[3][r] + b2f(*(const unsigned short*)(smem + xrb + 768));
            float ea = __expf(-vf);
            float ei = __expf(-vi);
            float eb = __expf(-2.0f * vc);
            float eo = __expf(-vo);
            float rf = __builtin_amdgcn_rcpf(1.0f + ea);
            float it = (1.0f - eb) * __builtin_amdgcn_rcpf((1.0f + ei) * (1.0f + eb));
            float cn = fmaf(rf, c[r], it);
            c[r] = cn;
            float ed = __expf(-2.0f * cn);
            float h = (1.0f - ed) * __builtin_amdgcn_rcpf((1.0f + eo) * (1.0f + ed));
            hu[r] = f2b(h);
            *(unsigned short*)(smem + hbn + (4 * hi + r) * 528 + (half * 128 + uin) * 2) = hu[r];
        }
        // publish own half: even lanes store packed u32 (device-coherent)
        #pragma unroll
        for (int r = 0; r < 4; ++r) {
            int ot = __shfl_xor((int)hu[r], 1);
            if ((ln & 1) == 0) {
                unsigned int pv = (unsigned int)hu[r] | ((unsigned int)ot << 16);
                const size_t di = ((size_t)(cur * 8 + g) * 2 + half) * 1024
                                + (4 * hi + r) * 64 + (uin >> 1);
                __hip_atomic_store((unsigned int*)hx + di, pv,
                                   __ATOMIC_RELAXED, __HIP_MEMORY_SCOPE_AGENT);
            }
        }
        // write next xp tile to LDS (its buffer is no longer read this step)
        if (do_stage) {
            *(short8*)(smem + xnxt + xdst)      = sv0;
            *(short8*)(smem + xnxt + xdst + 16) = sv1;
        }
        __syncthreads();   // drains vmcnt per wave before barrier -> stores visible
        if (tid == 0)
            __hip_atomic_store(mf, (unsigned)(t + 1), __ATOMIC_RELEASE, __HIP_MEMORY_SCOPE_AGENT);
    }

    // epilogue: partial FC over own 128 units, atomicAdd (2 deterministic addends)
    if (tid < 32) {
        const int r = tid >> 1, o = tid & 1;
        float s = (half == 0) ? fc_b[o] : 0.0f;
        const char* hrow = smem + 65536 + r * 528 + half * 256;  // h(511) lives in buf0
        for (int j = 0; j < 128; ++j)
            s += b2f(*(const unsigned short*)(hrow + j * 2)) * fc_w[o * HID + half * 128 + j];
        atomicAdd(&out[(16 * g + r) * 2 + o], s);
    }
}

extern "C" void kernel_launch(void* const* d_in, const int* in_sizes, int n_in,
                              void* d_out, int out_size, void* d_ws, size_t ws_size,
                              hipStream_t stream) {
    const int*   tokens = (const int*)  d_in[0];
    const float* emb    = (const float*)d_in[1];
    const float* W_x    = (const float*)d_in[2];
    const float* b_x    = (const float*)d_in[3];
    const float* U_h    = (const float*)d_in[4];
    const float* b_u    = (const float*)d_in[5];
    const float* b_g    = (const float*)d_in[6];
    const float* fc_w   = (const float*)d_in[7];
    const float* fc_b   = (const float*)d_in[8];
    float* out = (float*)d_out;

    char* ws = (char*)d_ws;
    unsigned short* w_xb  = (unsigned short*)(ws);                 // 512 KB
    unsigned short* u_hb  = (unsigned short*)(ws + 524288);        // 512 KB
    float*          bias  = (float*)(ws + 1048576);                // 4 KB
    unsigned int*   flags = (unsigned int*)(ws + 1052672);         // 64 B (pad 4 KB)
    unsigned short* hx    = (unsigned short*)(ws + 1056768);       // 128 KB [2][8][2][16][128]
    unsigned short* xp    = (unsigned short*)(ws + 1187840);       // 128 MB bf16 [S][B][4H]

    prep_kernel<<<1024, 256, 0, stream>>>(W_x, U_h, b_x, b_u, b_g, w_xb, u_hb, bias,
                                          flags, (unsigned int*)hx, out);
    xp_gemm<<<1024, 256, 0, stream>>>(tokens, emb, w_xb, bias, xp);

    (void)hipFuncSetAttribute((const void*)lstm_recur,
                              hipFuncAttributeMaxDynamicSharedMemorySize, 131072);
    lstm_recur<<<16, 512, 131072, stream>>>(xp, u_hb, fc_w, fc_b, hx, flags, out);
}

// Round 10
// 1242.224 us; speedup vs baseline: 2.1725x; 1.7120x over previous
//
#include <hip/hip_runtime.h>

typedef short short8 __attribute__((ext_vector_type(8)));
typedef float f4 __attribute__((ext_vector_type(4)));

#define BATCH 128
#define SEQ   512
#define EMB   256
#define HID   256
#define G4    1024   // 4*HID

static __device__ __forceinline__ unsigned short f2b(float f) {
    union { float f; unsigned int u; } v; v.f = f;
    unsigned int u = v.u;
    return (unsigned short)((u + 0x7FFFu + ((u >> 16) & 1u)) >> 16);  // RNE
}
static __device__ __forceinline__ float b2f(unsigned short s) {
    union { unsigned int u; float f; } v; v.u = ((unsigned int)s) << 16;
    return v.f;
}

// ---------------- Kernel 0: convert weights, fold biases, zero sync state -------
__global__ void prep_kernel(const float* __restrict__ W_x, const float* __restrict__ U_h,
                            const float* __restrict__ b_x, const float* __restrict__ b_u,
                            const float* __restrict__ b_g,
                            unsigned short* __restrict__ w_xb, unsigned short* __restrict__ u_hb,
                            float* __restrict__ bias,
                            unsigned int* __restrict__ hx32, float* __restrict__ out) {
    int i = blockIdx.x * blockDim.x + threadIdx.x;
    if (i < G4 * EMB) w_xb[i] = f2b(W_x[i]);
    if (i < G4 * HID) u_hb[i] = f2b(U_h[i]);
    if (i < G4) bias[i] = b_x[i] + b_u[i] + b_g[i];
    if (i < 65536) hx32[i] = 0;      // tag=0 everywhere (re-zeroed EVERY launch)
    if (i < 256) out[i] = 0.0f;      // out is atomicAdd-accumulated
}

// ---------------- Kernel 1: xp[s][b][g] = emb[tokens[b,s]] @ W_x^T + bias --------
__global__ __launch_bounds__(256) void xp_gemm(
    const int* __restrict__ tokens, const float* __restrict__ emb,
    const unsigned short* __restrict__ w_xb, const float* __restrict__ bias,
    unsigned short* __restrict__ xp)
{
    __shared__ unsigned short As[64][264];   // A tile
    __shared__ unsigned short Bs[64][264];   // staged B slice
    __shared__ unsigned short Xs[64][72];    // store-transpose bounce
    const int m0 = blockIdx.x * 64;
    const int b  = m0 >> 9;          // m0 / SEQ
    const int s0 = m0 & 511;         // m0 % SEQ
    const int tid = threadIdx.x;
    const int cS = tid >> 2, qS = (tid & 3) * 64;   // staging map (A and B)
    {
        const int tok = tokens[m0 + cS];
        const float* src = emb + (long)tok * EMB + qS;
        #pragma unroll
        for (int i = 0; i < 8; ++i) {
            float4 v0 = ((const float4*)src)[2 * i];
            float4 v1 = ((const float4*)src)[2 * i + 1];
            short8 pk;
            pk[0] = (short)f2b(v0.x); pk[1] = (short)f2b(v0.y);
            pk[2] = (short)f2b(v0.z); pk[3] = (short)f2b(v0.w);
            pk[4] = (short)f2b(v1.x); pk[5] = (short)f2b(v1.y);
            pk[6] = (short)f2b(v1.z); pk[7] = (short)f2b(v1.w);
            *(short8*)&As[cS][qS + i * 8] = pk;
        }
    }
    __syncthreads();
    const int w = tid >> 6, l = tid & 63;
    const int ln = l & 15, hi = l >> 4;
    short8 a[8];
    #pragma unroll
    for (int kk = 0; kk < 8; ++kk)
        a[kk] = *(const short8*)&As[16 * w + ln][kk * 32 + hi * 8];

    const int rl = tid >> 2;            // global-store row (own wave's rows)
    const int cl = (tid & 3) * 16;      // global-store col offset in 64-tile

    for (int n0 = 0; n0 < G4; n0 += 64) {
        {
            const unsigned short* src = &w_xb[(size_t)(n0 + cS) * EMB + qS];
            #pragma unroll
            for (int i = 0; i < 8; ++i)
                *(short8*)&Bs[cS][qS + i * 8] = *(const short8*)&src[i * 8];
        }
        __syncthreads();
        f4 acc[4] = {};
        #pragma unroll
        for (int kk = 0; kk < 8; ++kk) {
            #pragma unroll
            for (int nn = 0; nn < 4; ++nn) {
                short8 bfr = *(const short8*)&Bs[nn * 16 + ln][kk * 32 + hi * 8];
                acc[nn] = __builtin_amdgcn_mfma_f32_16x16x32_bf16(a[kk], bfr, acc[nn], 0, 0, 0);
            }
        }
        #pragma unroll
        for (int nn = 0; nn < 4; ++nn) {
            const float bs = bias[n0 + nn * 16 + ln];
            #pragma unroll
            for (int r = 0; r < 4; ++r)
                Xs[16 * w + 4 * hi + r][nn * 16 + ln] = f2b(acc[nn][r] + bs);
        }
        size_t off = ((size_t)(s0 + rl) * BATCH + b) * G4 + n0 + cl;
        *(short8*)&xp[off]     = *(const short8*)&Xs[rl][cl];
        *(short8*)&xp[off + 8] = *(const short8*)&Xs[rl][cl + 8];
        __syncthreads();
    }
}

// ---------------- Kernel 2: LSTM, 16 blocks = 8 batch-groups x 2 unit-halves ----
// Block (g=bid&7, half=bid>>3): batch rows 16g..+16, units half*128..+128.
// B-half (256 KB): 6 K-slices in 96 VGPRs, 2 in LDS (64 KB).
// Exchange protocol (ONE L3 trip, no fences, no L2 invalidates):
//   publish u32 word = (h_bf16<<16) | (t+1); consumer RELAXED-polls its own
//   words until tag==t (per-word atomicity = self-validating). Parity dbuf
//   prevents ABA: partner re-tags a parity word only after consuming our next
//   publish, which is __syncthreads-ordered after our read.
// LDS map: Blds [0,65536) | hb 2x8448 @65536/81920 (^16384) | xlds 2x16384 @98304 (^16384)
__global__ void __launch_bounds__(512, 2)
lstm_recur(const unsigned short* __restrict__ xp,
           const unsigned short* __restrict__ u_hb,
           const float* __restrict__ fc_w, const float* __restrict__ fc_b,
           unsigned int* __restrict__ hxw, float* __restrict__ out)
{
    extern __shared__ char smem[];
    const int tid = threadIdx.x;
    const int w = tid >> 6, l = tid & 63;
    const int ln = l & 15, hi = l >> 4;
    const int bid = blockIdx.x;
    const int g = bid & 7, half = bid >> 3, ph = half ^ 1;
    const int k_own = 4 * half, k_par = 4 * ph;   // K-slice bases (units = K dim)

    // preload B regs: own slices k_own+{0,1,2}, partner k_par+{0,1,2} (96 VGPRs)
    short8 Br[6][4];
    #pragma unroll
    for (int j = 0; j < 6; ++j) {
        const int kk = (j < 3) ? (k_own + j) : (k_par + j - 3);
        #pragma unroll
        for (int q = 0; q < 4; ++q) {
            const int col = q * 256 + half * 128 + w * 16 + ln;
            Br[j][q] = *(const short8*)&u_hb[(size_t)col * HID + kk * 32 + hi * 8];
        }
    }
    // B LDS: kkL0 = k_own+3, kkL1 = k_par+3 (lane-private frags, 64 KB)
    #pragma unroll
    for (int kkL = 0; kkL < 2; ++kkL) {
        const int kk = (kkL == 0) ? (k_own + 3) : (k_par + 3);
        #pragma unroll
        for (int q = 0; q < 4; ++q) {
            const int col = q * 256 + half * 128 + w * 16 + ln;
            *(short8*)(smem + kkL * 32768 + w * 4096 + q * 1024 + l * 16) =
                *(const short8*)&u_hb[(size_t)col * HID + kk * 32 + hi * 8];
        }
    }
    // zero both h buffers (2 x 8448 B @ 65536/81920)
    for (int i = tid; i < 4224; i += 512) ((unsigned*)(smem + 65536))[i] = 0;
    for (int i = tid; i < 4224; i += 512) ((unsigned*)(smem + 81920))[i] = 0;

    // xp staging geometry: thread -> (row = tid>>5, two 16B segs)
    const int row = tid >> 5, sseg = (tid & 31) * 2;
    const size_t xoff = (size_t)(16 * g + row) * 1024 + (sseg >> 4) * 256 + half * 128 + (sseg & 15) * 8;
    const int xdst = row * 1024 + sseg * 16;   // byte offset within xlds buffer
    {
        const unsigned short* src = xp + xoff;
        *(short8*)(smem + 98304 + xdst)      = *(const short8*)src;
        *(short8*)(smem + 98304 + xdst + 16) = *(const short8*)(src + 8);
    }
    __syncthreads();

    // copy-in mapping: thread -> (row crow, 4 units cuo..cuo+3) of partner half
    const int crow = tid >> 5, cuo = (tid & 31) * 4;
    // gate-cell mapping: lane -> rows 4hi..4hi+4, unit w*16+ln (+half*128 global)
    const int uin = w * 16 + ln;           // unit index within half
    float c[4] = {0.f, 0.f, 0.f, 0.f};

    for (int t = 0; t < SEQ; ++t) {
        const int cur = t & 1;
        const int hbc = 65536 + (cur << 14);
        const int hbn = hbc ^ 16384;
        const int xcur = 98304 + (cur << 14);
        const int xnxt = xcur ^ 16384;

        // prefetch next xp tile into regs (written to LDS at step end)
        short8 sv0, sv1;
        const bool do_stage = (t + 1 < SEQ);
        if (do_stage) {
            const unsigned short* src = xp + (size_t)(t + 1) * 131072 + xoff;
            sv0 = *(const short8*)src;
            sv1 = *(const short8*)(src + 8);
        }

        // prefetch-issue partner words (checked after own-half MFMA)
        unsigned int w0 = 0, w1 = 0, w2 = 0, w3 = 0;
        unsigned int* psrc = hxw;
        if (t > 0) {
            psrc = hxw + ((size_t)((cur ^ 1) * 8 + g) * 2 + ph) * 2048 + crow * 128 + cuo;
            w0 = __hip_atomic_load(psrc + 0, __ATOMIC_RELAXED, __HIP_MEMORY_SCOPE_AGENT);
            w1 = __hip_atomic_load(psrc + 1, __ATOMIC_RELAXED, __HIP_MEMORY_SCOPE_AGENT);
            w2 = __hip_atomic_load(psrc + 2, __ATOMIC_RELAXED, __HIP_MEMORY_SCOPE_AGENT);
            w3 = __hip_atomic_load(psrc + 3, __ATOMIC_RELAXED, __HIP_MEMORY_SCOPE_AGENT);
        }

        // own-half MFMA (partner h not needed yet)
        f4 acc[4] = {};
        short8 av;
        #pragma unroll
        for (int j = 0; j < 3; ++j) {
            av = *(const short8*)(smem + hbc + ln * 528 + (k_own + j) * 64 + hi * 16);
            #pragma unroll
            for (int q = 0; q < 4; ++q)
                acc[q] = __builtin_amdgcn_mfma_f32_16x16x32_bf16(av, Br[j][q], acc[q], 0, 0, 0);
        }
        av = *(const short8*)(smem + hbc + ln * 528 + (k_own + 3) * 64 + hi * 16);
        #pragma unroll
        for (int q = 0; q < 4; ++q) {
            short8 bl = *(const short8*)(smem + w * 4096 + q * 1024 + l * 16);  // kkL0
            acc[q] = __builtin_amdgcn_mfma_f32_16x16x32_bf16(av, bl, acc[q], 0, 0, 0);
        }

        // wait for partner h(t-1): poll tagged words (RELAXED, single L3 trip)
        if (t > 0) {
            const unsigned int tag = (unsigned int)t;
            while ((((w0 ^ tag) | (w1 ^ tag) | (w2 ^ tag) | (w3 ^ tag)) & 0xffffu) != 0u) {
                w0 = __hip_atomic_load(psrc + 0, __ATOMIC_RELAXED, __HIP_MEMORY_SCOPE_AGENT);
                w1 = __hip_atomic_load(psrc + 1, __ATOMIC_RELAXED, __HIP_MEMORY_SCOPE_AGENT);
                w2 = __hip_atomic_load(psrc + 2, __ATOMIC_RELAXED, __HIP_MEMORY_SCOPE_AGENT);
                w3 = __hip_atomic_load(psrc + 3, __ATOMIC_RELAXED, __HIP_MEMORY_SCOPE_AGENT);
            }
            unsigned long long packed = (unsigned long long)(w0 >> 16)
                | ((unsigned long long)(w1 >> 16) << 16)
                | ((unsigned long long)(w2 >> 16) << 32)
                | ((unsigned long long)(w3 >> 16) << 48);
            *(unsigned long long*)(smem + hbc + crow * 528 + (ph * 128 + cuo) * 2) = packed;
        }
        __syncthreads();

        // partner-half MFMA
        #pragma unroll
        for (int j = 0; j < 3; ++j) {
            av = *(const short8*)(smem + hbc + ln * 528 + (k_par + j) * 64 + hi * 16);
            #pragma unroll
            for (int q = 0; q < 4; ++q)
                acc[q] = __builtin_amdgcn_mfma_f32_16x16x32_bf16(av, Br[3 + j][q], acc[q], 0, 0, 0);
        }
        av = *(const short8*)(smem + hbc + ln * 528 + (k_par + 3) * 64 + hi * 16);
        #pragma unroll
        for (int q = 0; q < 4; ++q) {
            short8 bl = *(const short8*)(smem + 32768 + w * 4096 + q * 1024 + l * 16);  // kkL1
            acc[q] = __builtin_amdgcn_mfma_f32_16x16x32_bf16(av, bl, acc[q], 0, 0, 0);
        }

        // gates: lane owns 4 cells (rows 4hi+r, unit uin) — xp read from LDS
        unsigned int* pdst = hxw + ((size_t)(cur * 8 + g) * 2 + half) * 2048 + (4 * hi) * 128 + uin;
        const unsigned int tagn = (unsigned int)(t + 1);
        #pragma unroll
        for (int r = 0; r < 4; ++r) {
            const int xrb = xcur + (4 * hi + r) * 1024 + uin * 2;
            float vf = acc[0][r] + b2f(*(const unsigned short*)(smem + xrb));
            float vi = acc[1][r] + b2f(*(const unsigned short*)(smem + xrb + 256));
            float vc = acc[2][r] + b2f(*(const unsigned short*)(smem + xrb + 512));
            float vo = acc[3][r] + b2f(*(const unsigned short*)(smem + xrb + 768));
            float ea = __expf(-vf);
            float ei = __expf(-vi);
            float eb = __expf(-2.0f * vc);
            float eo = __expf(-vo);
            float rf = __builtin_amdgcn_rcpf(1.0f + ea);
            float it = (1.0f - eb) * __builtin_amdgcn_rcpf((1.0f + ei) * (1.0f + eb));
            float cn = fmaf(rf, c[r], it);
            c[r] = cn;
            float ed = __expf(-2.0f * cn);
            float h = (1.0f - ed) * __builtin_amdgcn_rcpf((1.0f + eo) * (1.0f + ed));
            unsigned short hb16 = f2b(h);
            *(unsigned short*)(smem + hbn + (4 * hi + r) * 528 + (half * 128 + uin) * 2) = hb16;
            // publish tagged word (fire-and-forget, no fence needed)
            __hip_atomic_store(pdst + r * 128, ((unsigned int)hb16 << 16) | tagn,
                               __ATOMIC_RELAXED, __HIP_MEMORY_SCOPE_AGENT);
        }
        // write next xp tile to LDS (its buffer is no longer read this step)
        if (do_stage) {
            *(short8*)(smem + xnxt + xdst)      = sv0;
            *(short8*)(smem + xnxt + xdst + 16) = sv1;
        }
        __syncthreads();
    }

    // epilogue: partial FC over own 128 units, atomicAdd (2 deterministic addends)
    if (tid < 32) {
        const int r = tid >> 1, o = tid & 1;
        float s = (half == 0) ? fc_b[o] : 0.0f;
        const char* hrow = smem + 65536 + r * 528 + half * 256;  // h(511) lives in buf0
        for (int j = 0; j < 128; ++j)
            s += b2f(*(const unsigned short*)(hrow + j * 2)) * fc_w[o * HID + half * 128 + j];
        atomicAdd(&out[(16 * g + r) * 2 + o], s);
    }
}

extern "C" void kernel_launch(void* const* d_in, const int* in_sizes, int n_in,
                              void* d_out, int out_size, void* d_ws, size_t ws_size,
                              hipStream_t stream) {
    const int*   tokens = (const int*)  d_in[0];
    const float* emb    = (const float*)d_in[1];
    const float* W_x    = (const float*)d_in[2];
    const float* b_x    = (const float*)d_in[3];
    const float* U_h    = (const float*)d_in[4];
    const float* b_u    = (const float*)d_in[5];
    const float* b_g    = (const float*)d_in[6];
    const float* fc_w   = (const float*)d_in[7];
    const float* fc_b   = (const float*)d_in[8];
    float* out = (float*)d_out;

    char* ws = (char*)d_ws;
    unsigned short* w_xb  = (unsigned short*)(ws);                 // 512 KB
    unsigned short* u_hb  = (unsigned short*)(ws + 524288);        // 512 KB
    float*          bias  = (float*)(ws + 1048576);                // 4 KB
    unsigned int*   hxw   = (unsigned int*)(ws + 1052672);         // 256 KB [2][8][2][16][128] u32
    unsigned short* xp    = (unsigned short*)(ws + 1314816);       // 128 MB bf16 [S][B][4H]

    prep_kernel<<<1024, 256, 0, stream>>>(W_x, U_h, b_x, b_u, b_g, w_xb, u_hb, bias,
                                          hxw, out);
    xp_gemm<<<1024, 256, 0, stream>>>(tokens, emb, w_xb, bias, xp);

    (void)hipFuncSetAttribute((const void*)lstm_recur,
                              hipFuncAttributeMaxDynamicSharedMemorySize, 131072);
    lstm_recur<<<16, 512, 131072, stream>>>(xp, u_hb, fc_w, fc_b, hxw, out);
}